// Round 15
// baseline (324.974 us; speedup 1.0000x reference)
//
#include <hip/hip_runtime.h>

#define NR 1024        // num rois
#define NFG 80         // fg classes
#define CC 81          // total classes
#define KDIM 2048
#define H1DIM 256
#define H3DIM 512
#define D4 324         // 4*81
#define NCOMB 768      // 256 + 512 combined output cols
#define SKM 4          // split-K for main GEMM
#define SKD 8          // split-K for deltas GEMM

typedef unsigned long long u64;

// ---------------- main GEMM partials: P[ks][1024][768] = X @ [w1|w3] (round-13 config) -----
__global__ __launch_bounds__(128) void gemm_main_kernel(
    const float* __restrict__ X, const float* __restrict__ w1,
    const float* __restrict__ w3, float* __restrict__ P)
{
    const int nb = blockIdx.x;
    const int mb = blockIdx.y;
    const int ks = blockIdx.z;
    const float* B; int Ncols, colbase;
    if (nb < 4) { B = w1; Ncols = H1DIM; colbase = nb * 64; }
    else        { B = w3; Ncols = H3DIM; colbase = (nb - 4) * 64; }
    const int row0 = mb * 64;
    const int wv = threadIdx.x >> 6;
    const int lane = threadIdx.x & 63;
    const int kstart = ks * 512 + wv * 256;

    __shared__ float As[2][32][64];
    __shared__ float Bs[2][32][64];

    const int tx = lane & 7;
    const int ty = lane >> 3;
    const int rg = lane & 15;
    const int kg = lane >> 4;
    const int brow = lane >> 4;
    const int bcol4 = (lane & 15) * 4;

    float acc[8][8] = {};
    float4 ca[8], cb[8];

#pragma unroll
    for (int jj = 0; jj < 2; jj++)
#pragma unroll
        for (int rr = 0; rr < 4; rr++)
            ca[jj * 4 + rr] = *reinterpret_cast<const float4*>(
                &X[(size_t)(row0 + rg * 4 + rr) * KDIM + kstart + kg * 4 + jj * 16]);
#pragma unroll
    for (int j = 0; j < 8; j++)
        cb[j] = *reinterpret_cast<const float4*>(
            &B[(size_t)(kstart + brow + j * 4) * Ncols + colbase + bcol4]);

    for (int kt = 0; kt < 8; kt++) {
#pragma unroll
        for (int jj = 0; jj < 2; jj++) {
            const int kb = kg * 4 + jj * 16;
            float4 w0 = make_float4(ca[jj*4+0].x, ca[jj*4+1].x, ca[jj*4+2].x, ca[jj*4+3].x);
            float4 w1_ = make_float4(ca[jj*4+0].y, ca[jj*4+1].y, ca[jj*4+2].y, ca[jj*4+3].y);
            float4 w2_ = make_float4(ca[jj*4+0].z, ca[jj*4+1].z, ca[jj*4+2].z, ca[jj*4+3].z);
            float4 w3_ = make_float4(ca[jj*4+0].w, ca[jj*4+1].w, ca[jj*4+2].w, ca[jj*4+3].w);
            *reinterpret_cast<float4*>(&As[wv][kb + 0][rg * 4]) = w0;
            *reinterpret_cast<float4*>(&As[wv][kb + 1][rg * 4]) = w1_;
            *reinterpret_cast<float4*>(&As[wv][kb + 2][rg * 4]) = w2_;
            *reinterpret_cast<float4*>(&As[wv][kb + 3][rg * 4]) = w3_;
        }
#pragma unroll
        for (int j = 0; j < 8; j++)
            *reinterpret_cast<float4*>(&Bs[wv][brow + j * 4][bcol4]) = cb[j];

        if (kt < 7) {
            const int kof = kstart + (kt + 1) * 32;
#pragma unroll
            for (int jj = 0; jj < 2; jj++)
#pragma unroll
                for (int rr = 0; rr < 4; rr++)
                    ca[jj * 4 + rr] = *reinterpret_cast<const float4*>(
                        &X[(size_t)(row0 + rg * 4 + rr) * KDIM + kof + kg * 4 + jj * 16]);
#pragma unroll
            for (int j = 0; j < 8; j++)
                cb[j] = *reinterpret_cast<const float4*>(
                    &B[(size_t)(kof + brow + j * 4) * Ncols + colbase + bcol4]);
        }

#pragma unroll 8
        for (int kk = 0; kk < 32; kk++) {
            float4 a0 = *reinterpret_cast<const float4*>(&As[wv][kk][ty * 8]);
            float4 a1 = *reinterpret_cast<const float4*>(&As[wv][kk][ty * 8 + 4]);
            float4 b0 = *reinterpret_cast<const float4*>(&Bs[wv][kk][tx * 8]);
            float4 b1 = *reinterpret_cast<const float4*>(&Bs[wv][kk][tx * 8 + 4]);
            float av[8] = {a0.x, a0.y, a0.z, a0.w, a1.x, a1.y, a1.z, a1.w};
            float bv[8] = {b0.x, b0.y, b0.z, b0.w, b1.x, b1.y, b1.z, b1.w};
#pragma unroll
            for (int i = 0; i < 8; i++)
#pragma unroll
                for (int j = 0; j < 8; j++)
                    acc[i][j] += av[i] * bv[j];
        }
    }

    float* comb = &As[0][0][0];
    __syncthreads();
    if (wv == 1) {
#pragma unroll
        for (int i = 0; i < 8; i++) {
            const int row = ty * 8 + i;
            *reinterpret_cast<float4*>(&comb[row * 64 + tx * 8]) =
                make_float4(acc[i][0], acc[i][1], acc[i][2], acc[i][3]);
            *reinterpret_cast<float4*>(&comb[row * 64 + tx * 8 + 4]) =
                make_float4(acc[i][4], acc[i][5], acc[i][6], acc[i][7]);
        }
    }
    __syncthreads();
    if (wv == 0) {
        const int ccol = nb * 64 + tx * 8;
#pragma unroll
        for (int i = 0; i < 8; i++) {
            const int row = ty * 8 + i;
            float4 c0 = *reinterpret_cast<const float4*>(&comb[row * 64 + tx * 8]);
            float4 c1 = *reinterpret_cast<const float4*>(&comb[row * 64 + tx * 8 + 4]);
            float* pr = &P[((size_t)ks * NR + row0 + row) * NCOMB + ccol];
            *reinterpret_cast<float4*>(&pr[0]) = make_float4(
                acc[i][0] + c0.x, acc[i][1] + c0.y, acc[i][2] + c0.z, acc[i][3] + c0.w);
            *reinterpret_cast<float4*>(&pr[4]) = make_float4(
                acc[i][4] + c1.x, acc[i][5] + c1.y, acc[i][6] + c1.z, acc[i][7] + c1.w);
        }
    }
}

// ---------------- reduce: H3 = relu(sum_ks P[.][256:768] + b3) ----------------
__global__ __launch_bounds__(256) void reduce_h3_kernel(
    const float* __restrict__ P, const float* __restrict__ b3, float* __restrict__ H3)
{
    const int idx = blockIdx.x * 256 + threadIdx.x;
    if (idx >= NR * H3DIM / 4) return;
    const int row = idx / (H3DIM / 4);
    const int col = (idx % (H3DIM / 4)) * 4;
    const size_t off = (size_t)row * NCOMB + H1DIM + col;
    float4 s = *reinterpret_cast<const float4*>(&P[off]);
#pragma unroll
    for (int ksplit = 1; ksplit < SKM; ksplit++) {
        float4 p = *reinterpret_cast<const float4*>(&P[(size_t)ksplit * NR * NCOMB + off]);
        s.x += p.x; s.y += p.y; s.z += p.z; s.w += p.w;
    }
    float4 bb = *reinterpret_cast<const float4*>(&b3[col]);
    s.x = fmaxf(s.x + bb.x, 0.f); s.y = fmaxf(s.y + bb.y, 0.f);
    s.z = fmaxf(s.z + bb.z, 0.f); s.w = fmaxf(s.w + bb.w, 0.f);
    *reinterpret_cast<float4*>(&H3[row * H3DIM + col]) = s;
}

// ---------------- scores: h1 = relu(sum_ks P[.][0:256] + b1); softmax(h1 @ w2 + b2) --------
__global__ __launch_bounds__(128) void scores_softmax_kernel(
    const float* __restrict__ P, const float* __restrict__ b1,
    const float* __restrict__ w2, const float* __restrict__ b2,
    float* __restrict__ probs)
{
    const int r = blockIdx.x;
    const int t = threadIdx.x;
    __shared__ float h[H1DIM];
    __shared__ float lg[CC];
    __shared__ float red[128];

    for (int k = t; k < H1DIM; k += 128) {
        float s = P[(size_t)r * NCOMB + k];
#pragma unroll
        for (int ksplit = 1; ksplit < SKM; ksplit++)
            s += P[((size_t)ksplit * NR + r) * NCOMB + k];
        h[k] = fmaxf(s + b1[k], 0.f);
    }
    __syncthreads();

    if (t < CC) {
        float acc = b2[t];
        for (int k = 0; k < H1DIM; k++) acc += h[k] * w2[k * CC + t];
        lg[t] = acc;
    }
    __syncthreads();

    red[t] = (t < CC) ? lg[t] : -1e30f;
    __syncthreads();
    for (int s = 64; s > 0; s >>= 1) {
        if (t < s) red[t] = fmaxf(red[t], red[t + s]);
        __syncthreads();
    }
    float mx = red[0];
    __syncthreads();

    float e = 0.f;
    if (t < CC) e = expf(lg[t] - mx);
    red[t] = e;
    __syncthreads();
    for (int s = 64; s > 0; s >>= 1) {
        if (t < s) red[t] += red[t + s];
        __syncthreads();
    }
    float sum = red[0];

    if (t >= 1 && t < CC) probs[(t - 1) * NR + r] = e / sum;
}

// ---------------- deltas GEMM partials: Pd[ks][1024][324] = H3 @ w4 (round-13 config) ------
__global__ __launch_bounds__(64) void gemm_delta_kernel(
    const float* __restrict__ H3, const float* __restrict__ w4, float* __restrict__ Pd)
{
    const int nb = blockIdx.x;
    const int mb = blockIdx.y;
    const int ks = blockIdx.z;
    const int colbase = nb * 64;
    const int row0 = mb * 64;
    const int kstart = ks * 64;

    __shared__ float As[32][64];
    __shared__ float Bs[32][64];
    const int t = threadIdx.x;
    const int tx = t & 7;
    const int ty = t >> 3;
    const int brow = t >> 4;
    const int bcol4 = (t & 15) * 4;
    const int bcol_src = min(colbase + bcol4, D4 - 4);

    float acc[8][8] = {};
    float4 ca[8], cb[8];
    const float* Ar = &H3[(row0 + t) * H3DIM + kstart];

#pragma unroll
    for (int j = 0; j < 8; j++) {
        ca[j] = *reinterpret_cast<const float4*>(&Ar[j * 4]);
        cb[j] = *reinterpret_cast<const float4*>(&w4[(kstart + brow + j * 4) * D4 + bcol_src]);
    }

    for (int kt = 0; kt < 2; kt++) {
#pragma unroll
        for (int j = 0; j < 8; j++) {
            As[j * 4 + 0][t] = ca[j].x;
            As[j * 4 + 1][t] = ca[j].y;
            As[j * 4 + 2][t] = ca[j].z;
            As[j * 4 + 3][t] = ca[j].w;
            *reinterpret_cast<float4*>(&Bs[brow + j * 4][bcol4]) = cb[j];
        }
        if (kt < 1) {
            const int kn = kstart + 32;
#pragma unroll
            for (int j = 0; j < 8; j++) {
                ca[j] = *reinterpret_cast<const float4*>(&Ar[32 + j * 4]);
                cb[j] = *reinterpret_cast<const float4*>(&w4[(kn + brow + j * 4) * D4 + bcol_src]);
            }
        }
#pragma unroll 8
        for (int kk = 0; kk < 32; kk++) {
            float4 a0 = *reinterpret_cast<const float4*>(&As[kk][ty * 8]);
            float4 a1 = *reinterpret_cast<const float4*>(&As[kk][ty * 8 + 4]);
            float4 b0 = *reinterpret_cast<const float4*>(&Bs[kk][tx * 8]);
            float4 b1 = *reinterpret_cast<const float4*>(&Bs[kk][tx * 8 + 4]);
            float av[8] = {a0.x, a0.y, a0.z, a0.w, a1.x, a1.y, a1.z, a1.w};
            float bv[8] = {b0.x, b0.y, b0.z, b0.w, b1.x, b1.y, b1.z, b1.w};
#pragma unroll
            for (int i = 0; i < 8; i++)
#pragma unroll
                for (int j = 0; j < 8; j++)
                    acc[i][j] += av[i] * bv[j];
        }
    }

    const int pcol0 = colbase + tx * 8;
#pragma unroll
    for (int i = 0; i < 8; i++) {
        const int row = row0 + ty * 8 + i;
        float* pr = &Pd[((size_t)ks * NR + row) * D4 + pcol0];
        if (pcol0 + 4 <= D4)
            *reinterpret_cast<float4*>(&pr[0]) = make_float4(acc[i][0], acc[i][1], acc[i][2], acc[i][3]);
        if (pcol0 + 8 <= D4)
            *reinterpret_cast<float4*>(&pr[4]) = make_float4(acc[i][4], acc[i][5], acc[i][6], acc[i][7]);
    }
}

// ---------------- A: per-class compact -> rank -> decode -> write sorted boxes/scores/V ----
__global__ __launch_bounds__(512) void sort_decode_kernel(
    const float* __restrict__ probs, const float* __restrict__ Pd,
    const float* __restrict__ b4, const float* __restrict__ rois,
    const float* __restrict__ im_info, float* __restrict__ ssg,
    float* __restrict__ sboxes, int* __restrict__ Vg)
{
    const int c = blockIdx.x;
    const int t = threadIdx.x;
    const int lane = t & 63;

    __shared__ float imv[3];
    __shared__ float cs_sc[NR];
    __shared__ int   cs_ix[NR];
    __shared__ float ss[NR];
    __shared__ int   sx[NR];
    __shared__ int vcount;

    if (t < 3) imv[t] = im_info[t];
    if (t == 0) vcount = 0;
    __syncthreads();

    // ballot-compact valid entries
    for (int i = t; i < NR; i += 512) {
        float s = probs[c * NR + i];
        bool valid = (s > 0.05f);
        u64 m = __ballot(valid ? 1 : 0);
        int wbase = 0;
        if (lane == 0 && m) wbase = atomicAdd(&vcount, __popcll(m));
        wbase = __shfl(wbase, 0, 64);
        if (valid) {
            int p = wbase + __popcll(m & ((1ULL << lane) - 1ULL));
            cs_sc[p] = s; cs_ix[p] = i;
        }
    }
    __syncthreads();
    const int V = vcount;

    // thread-per-entry exact stable rank (LDS broadcast inner loop)
    for (int e = t; e < V; e += 512) {
        const float se = cs_sc[e];
        const int   ie = cs_ix[e];
        int cnt = 0;
        for (int f = 0; f < V; f++) {
            float sf = cs_sc[f];
            int   jf = cs_ix[f];
            cnt += (sf > se || (sf == se && jf < ie)) ? 1 : 0;
        }
        ss[cnt] = se; sx[cnt] = ie;
    }
    __syncthreads();

    // decode + write sorted boxes/scores to global
    const float Hm1 = imv[0] - 1.f, Wm1 = imv[1] - 1.f, inv = 1.f / imv[2];
    for (int i = t; i < V; i += 512) {
        const int r = sx[i];
        float4 dd = *reinterpret_cast<const float4*>(&Pd[(size_t)r * D4 + (c + 1) * 4]);
#pragma unroll
        for (int ksplit = 1; ksplit < SKD; ksplit++) {
            float4 p = *reinterpret_cast<const float4*>(&Pd[((size_t)ksplit * NR + r) * D4 + (c + 1) * 4]);
            dd.x += p.x; dd.y += p.y; dd.z += p.z; dd.w += p.w;
        }
        float4 b4c = *reinterpret_cast<const float4*>(&b4[(c + 1) * 4]);
        float dx = (dd.x + b4c.x) * 0.1f, dy = (dd.y + b4c.y) * 0.1f;
        float dw = (dd.z + b4c.z) * 0.2f, dh = (dd.w + b4c.w) * 0.2f;
        float x1 = rois[r * 5 + 1], y1 = rois[r * 5 + 2];
        float x2 = rois[r * 5 + 3], y2 = rois[r * 5 + 4];
        float wdt = x2 - x1 + 1.f, hgt = y2 - y1 + 1.f;
        float ctx = x1 + 0.5f * wdt, cty = y1 + 0.5f * hgt;
        float pcx = dx * wdt + ctx, pcy = dy * hgt + cty;
        float pw = expf(dw) * wdt, ph = expf(dh) * hgt;
        float b0 = fminf(fmaxf(pcx - 0.5f * pw, 0.f), Wm1) * inv;
        float b1v = fminf(fmaxf(pcy - 0.5f * ph, 0.f), Hm1) * inv;
        float b2v = fminf(fmaxf(pcx + 0.5f * pw, 0.f), Wm1) * inv;
        float b3v = fminf(fmaxf(pcy + 0.5f * ph, 0.f), Hm1) * inv;
        *reinterpret_cast<float4*>(&sboxes[((size_t)c * NR + i) * 4]) =
            make_float4(b0, b1v, b2v, b3v);
        ssg[c * NR + i] = ss[i];
    }
    if (t == 0) Vg[c] = V;
}

// ---------------- B: symmetric IoU bitmatrix, grid-parallel (16 row-chunks x 80 classes) ---
__global__ __launch_bounds__(512) void iou_mask_kernel(
    const float* __restrict__ sboxes, const int* __restrict__ Vg,
    u64* __restrict__ mask)
{
    const int rc = blockIdx.x;
    const int c = blockIdx.y;
    const int V = Vg[c];
    const int rowbase = rc * 64;
    if (rowbase >= V) return;

    __shared__ float bxs[NR][4];
    const int t = threadIdx.x;
    const int lane = t & 63;
    const int wave = t >> 6;

    for (int i = t; i < V; i += 512) {
        float4 b = *reinterpret_cast<const float4*>(&sboxes[((size_t)c * NR + i) * 4]);
        bxs[i][0] = b.x; bxs[i][1] = b.y; bxs[i][2] = b.z; bxs[i][3] = b.w;
    }
    __syncthreads();

    const int nrows = min(64, V - rowbase);
    const int wlim = (V + 63) >> 6;
    for (int r = wave; r < nrows; r += 8) {
        const int i = rowbase + r;
        const float x1i = bxs[i][0], y1i = bxs[i][1], x2i = bxs[i][2], y2i = bxs[i][3];
        const float ai = (x2i - x1i + 1.f) * (y2i - y1i + 1.f);
        for (int w = 0; w < 16; w++) {
            u64 bits = 0;
            if (w < wlim) {
                int j = w * 64 + lane;
                int pred = 0;
                if (j < V) {          // includes j == i -> self bit set (self-clearing scan)
                    float iw = fminf(x2i, bxs[j][2]) - fmaxf(x1i, bxs[j][0]) + 1.f;
                    float ih = fminf(y2i, bxs[j][3]) - fmaxf(y1i, bxs[j][1]) + 1.f;
                    if (iw > 0.f && ih > 0.f) {
                        float inter = iw * ih;
                        float aj = (bxs[j][2] - bxs[j][0] + 1.f) * (bxs[j][3] - bxs[j][1] + 1.f);
                        if (inter / (ai + aj - inter) > 0.3f) pred = 1;
                    }
                }
                bits = __ballot(pred);
            }
            if (lane == 0) mask[((size_t)c * NR + i) * 16 + w] = bits;
        }
    }
}

// ---------------- C: per-class greedy scan over LDS bitmatrix + emit ----------------
__global__ __launch_bounds__(512) void scan_emit_kernel(
    const float* __restrict__ ssg, const float* __restrict__ sboxes,
    const int* __restrict__ Vg, const u64* __restrict__ mask,
    float* __restrict__ out)
{
    const int c = blockIdx.x;
    const int V = Vg[c];
    const int t = threadIdx.x;
    __shared__ u64 ml[NR * 16];     // 128 KiB; rows 0..V-1; ml[0..15] reused for keep words

    for (int u = t; u < V * 16; u += 512)
        ml[u] = mask[(size_t)c * NR * 16 + u];
    __syncthreads();

    if (t == 0) {
        u64 a[16], k[16];
#pragma unroll
        for (int w = 0; w < 16; w++) {
            int rem = V - w * 64;
            a[w] = rem >= 64 ? ~0ULL : (rem > 0 ? ((1ULL << rem) - 1ULL) : 0ULL);
            k[w] = 0ULL;
        }
        while (true) {
            int fw = -1; u64 bits = 0;
#pragma unroll
            for (int w = 0; w < 16; w++)
                if (fw < 0 && a[w]) { fw = w; bits = a[w]; }
            if (fw < 0) break;
            int b = __builtin_ctzll(bits);
            int i = fw * 64 + b;
#pragma unroll
            for (int w = 0; w < 16; w++) {
                if (w == fw) k[w] |= (1ULL << b);
                a[w] &= ~ml[i * 16 + w];     // self bit set -> clears i too
            }
        }
#pragma unroll
        for (int w = 0; w < 16; w++) ml[w] = k[w];
    }
    __syncthreads();

    for (int i = t; i < NR; i += 512) {
        float2* o = reinterpret_cast<float2*>(&out[(size_t)(c * NR + i) * 6]);
        bool kp = (i < V) && ((ml[i >> 6] >> (i & 63)) & 1ULL);
        float2 p0, p1, p2;
        if (kp) {
            float4 bb = *reinterpret_cast<const float4*>(&sboxes[((size_t)c * NR + i) * 4]);
            p0 = make_float2(bb.x, bb.y);
            p1 = make_float2(bb.z, bb.w);
            p2 = make_float2(ssg[c * NR + i], (float)c);
        } else {
            p0 = make_float2(0.f, 0.f);
            p1 = make_float2(0.f, 0.f);
            p2 = make_float2(0.f, 0.f);
        }
        o[0] = p0; o[1] = p1; o[2] = p2;
    }
}

extern "C" void kernel_launch(void* const* d_in, const int* in_sizes, int n_in,
                              void* d_out, int out_size, void* d_ws, size_t ws_size,
                              hipStream_t stream)
{
    const float* X    = (const float*)d_in[0];
    const float* rois = (const float*)d_in[1];
    const float* imi  = (const float*)d_in[2];
    const float* w1   = (const float*)d_in[3];
    const float* b1   = (const float*)d_in[4];
    const float* w2   = (const float*)d_in[5];
    const float* b2   = (const float*)d_in[6];
    const float* w3   = (const float*)d_in[7];
    const float* b3   = (const float*)d_in[8];
    const float* w4   = (const float*)d_in[9];
    const float* b4   = (const float*)d_in[10];
    float* out = (float*)d_out;

    float* ws     = (float*)d_ws;
    float* H3     = ws;                          // 1024*512
    float* probs  = H3 + NR * H3DIM;             // 80*1024
    float* ssg    = probs + NFG * NR;            // 80*1024
    float* sboxes = ssg + NFG * NR;              // 80*1024*4
    int*   Vg     = (int*)(sboxes + (size_t)NFG * NR * 4);   // 128 ints
    float* P      = (float*)(Vg + 128);          // 4*1024*768 region; Pd then mask alias it

    gemm_main_kernel<<<dim3(12, 16, SKM), 128, 0, stream>>>(X, w1, w3, P);
    reduce_h3_kernel<<<(NR * H3DIM / 4 + 255) / 256, 256, 0, stream>>>(P, b3, H3);
    scores_softmax_kernel<<<NR, 128, 0, stream>>>(P, b1, w2, b2, probs);
    gemm_delta_kernel<<<dim3(6, 16, SKD), 64, 0, stream>>>(H3, w4, P);       // Pd over P
    sort_decode_kernel<<<NFG, 512, 0, stream>>>(probs, P, b4, rois, imi, ssg, sboxes, Vg);
    iou_mask_kernel<<<dim3(16, NFG), 512, 0, stream>>>(sboxes, Vg, (u64*)P); // mask over Pd
    scan_emit_kernel<<<NFG, 512, 0, stream>>>(ssg, sboxes, Vg, (u64*)P, out);
}

// Round 16
// 177.539 us; speedup vs baseline: 1.8304x; 1.8304x over previous
//
#include <hip/hip_runtime.h>

#define NR 1024        // num rois
#define NFG 80         // fg classes
#define CC 81          // total classes
#define KDIM 2048
#define H1DIM 256
#define H3DIM 512
#define D4 324         // 4*81
#define NCOMB 768      // 256 + 512 combined output cols
#define SKM 4          // split-K for main GEMM (K=2048 -> 512/block, 256/wave)
#define SKD 8          // split-K for deltas GEMM (K=512 -> 64/chunk)

typedef unsigned long long u64;

// ---------------- main GEMM partials: P[ks][1024][768] = X @ [w1|w3] (K-chunk ks) ----------
// Round-13 config (2-wave blocks, private LDS, no inner barriers) + XCD-chunked block
// swizzle: linear bid -> swz=(bid&7)*96+(bid>>3) gives each XCD a contiguous nb x mb run
// whose X-slice (~1MB) + B panels fit its 4MB L2 -> prefetch misses become L2 hits.
__global__ __launch_bounds__(128) void gemm_main_kernel(
    const float* __restrict__ X, const float* __restrict__ w1,
    const float* __restrict__ w3, float* __restrict__ P)
{
    const int bid = blockIdx.x;            // 0..767
    const int swz = (bid & 7) * 96 + (bid >> 3);
    const int nb = swz % 12;
    const int mb = (swz / 12) & 15;
    const int ks = swz / 192;

    const float* B; int Ncols, colbase;
    if (nb < 4) { B = w1; Ncols = H1DIM; colbase = nb * 64; }
    else        { B = w3; Ncols = H3DIM; colbase = (nb - 4) * 64; }
    const int row0 = mb * 64;
    const int wv = threadIdx.x >> 6;
    const int lane = threadIdx.x & 63;
    const int kstart = ks * 512 + wv * 256;

    __shared__ float As[2][32][64];
    __shared__ float Bs[2][32][64];

    const int tx = lane & 7;
    const int ty = lane >> 3;
    const int rg = lane & 15;
    const int kg = lane >> 4;
    const int brow = lane >> 4;
    const int bcol4 = (lane & 15) * 4;

    float acc[8][8] = {};
    float4 ca[8], cb[8];

#pragma unroll
    for (int jj = 0; jj < 2; jj++)
#pragma unroll
        for (int rr = 0; rr < 4; rr++)
            ca[jj * 4 + rr] = *reinterpret_cast<const float4*>(
                &X[(size_t)(row0 + rg * 4 + rr) * KDIM + kstart + kg * 4 + jj * 16]);
#pragma unroll
    for (int j = 0; j < 8; j++)
        cb[j] = *reinterpret_cast<const float4*>(
            &B[(size_t)(kstart + brow + j * 4) * Ncols + colbase + bcol4]);

    for (int kt = 0; kt < 8; kt++) {
#pragma unroll
        for (int jj = 0; jj < 2; jj++) {
            const int kb = kg * 4 + jj * 16;
            float4 w0 = make_float4(ca[jj*4+0].x, ca[jj*4+1].x, ca[jj*4+2].x, ca[jj*4+3].x);
            float4 w1_ = make_float4(ca[jj*4+0].y, ca[jj*4+1].y, ca[jj*4+2].y, ca[jj*4+3].y);
            float4 w2_ = make_float4(ca[jj*4+0].z, ca[jj*4+1].z, ca[jj*4+2].z, ca[jj*4+3].z);
            float4 w3_ = make_float4(ca[jj*4+0].w, ca[jj*4+1].w, ca[jj*4+2].w, ca[jj*4+3].w);
            *reinterpret_cast<float4*>(&As[wv][kb + 0][rg * 4]) = w0;
            *reinterpret_cast<float4*>(&As[wv][kb + 1][rg * 4]) = w1_;
            *reinterpret_cast<float4*>(&As[wv][kb + 2][rg * 4]) = w2_;
            *reinterpret_cast<float4*>(&As[wv][kb + 3][rg * 4]) = w3_;
        }
#pragma unroll
        for (int j = 0; j < 8; j++)
            *reinterpret_cast<float4*>(&Bs[wv][brow + j * 4][bcol4]) = cb[j];

        if (kt < 7) {
            const int kof = kstart + (kt + 1) * 32;
#pragma unroll
            for (int jj = 0; jj < 2; jj++)
#pragma unroll
                for (int rr = 0; rr < 4; rr++)
                    ca[jj * 4 + rr] = *reinterpret_cast<const float4*>(
                        &X[(size_t)(row0 + rg * 4 + rr) * KDIM + kof + kg * 4 + jj * 16]);
#pragma unroll
            for (int j = 0; j < 8; j++)
                cb[j] = *reinterpret_cast<const float4*>(
                    &B[(size_t)(kof + brow + j * 4) * Ncols + colbase + bcol4]);
        }

#pragma unroll 8
        for (int kk = 0; kk < 32; kk++) {
            float4 a0 = *reinterpret_cast<const float4*>(&As[wv][kk][ty * 8]);
            float4 a1 = *reinterpret_cast<const float4*>(&As[wv][kk][ty * 8 + 4]);
            float4 b0 = *reinterpret_cast<const float4*>(&Bs[wv][kk][tx * 8]);
            float4 b1 = *reinterpret_cast<const float4*>(&Bs[wv][kk][tx * 8 + 4]);
            float av[8] = {a0.x, a0.y, a0.z, a0.w, a1.x, a1.y, a1.z, a1.w};
            float bv[8] = {b0.x, b0.y, b0.z, b0.w, b1.x, b1.y, b1.z, b1.w};
#pragma unroll
            for (int i = 0; i < 8; i++)
#pragma unroll
                for (int j = 0; j < 8; j++)
                    acc[i][j] += av[i] * bv[j];
        }
    }

    float* comb = &As[0][0][0];
    __syncthreads();
    if (wv == 1) {
#pragma unroll
        for (int i = 0; i < 8; i++) {
            const int row = ty * 8 + i;
            *reinterpret_cast<float4*>(&comb[row * 64 + tx * 8]) =
                make_float4(acc[i][0], acc[i][1], acc[i][2], acc[i][3]);
            *reinterpret_cast<float4*>(&comb[row * 64 + tx * 8 + 4]) =
                make_float4(acc[i][4], acc[i][5], acc[i][6], acc[i][7]);
        }
    }
    __syncthreads();
    if (wv == 0) {
        const int ccol = nb * 64 + tx * 8;
#pragma unroll
        for (int i = 0; i < 8; i++) {
            const int row = ty * 8 + i;
            float4 c0 = *reinterpret_cast<const float4*>(&comb[row * 64 + tx * 8]);
            float4 c1 = *reinterpret_cast<const float4*>(&comb[row * 64 + tx * 8 + 4]);
            float* pr = &P[((size_t)ks * NR + row0 + row) * NCOMB + ccol];
            *reinterpret_cast<float4*>(&pr[0]) = make_float4(
                acc[i][0] + c0.x, acc[i][1] + c0.y, acc[i][2] + c0.z, acc[i][3] + c0.w);
            *reinterpret_cast<float4*>(&pr[4]) = make_float4(
                acc[i][4] + c1.x, acc[i][5] + c1.y, acc[i][6] + c1.z, acc[i][7] + c1.w);
        }
    }
}

// ---------------- reduce: H3 = relu(sum_ks P[.][256:768] + b3) ----------------
__global__ __launch_bounds__(256) void reduce_h3_kernel(
    const float* __restrict__ P, const float* __restrict__ b3, float* __restrict__ H3)
{
    const int idx = blockIdx.x * 256 + threadIdx.x;
    if (idx >= NR * H3DIM / 4) return;
    const int row = idx / (H3DIM / 4);
    const int col = (idx % (H3DIM / 4)) * 4;
    const size_t off = (size_t)row * NCOMB + H1DIM + col;
    float4 s = *reinterpret_cast<const float4*>(&P[off]);
#pragma unroll
    for (int ksplit = 1; ksplit < SKM; ksplit++) {
        float4 p = *reinterpret_cast<const float4*>(&P[(size_t)ksplit * NR * NCOMB + off]);
        s.x += p.x; s.y += p.y; s.z += p.z; s.w += p.w;
    }
    float4 bb = *reinterpret_cast<const float4*>(&b3[col]);
    s.x = fmaxf(s.x + bb.x, 0.f); s.y = fmaxf(s.y + bb.y, 0.f);
    s.z = fmaxf(s.z + bb.z, 0.f); s.w = fmaxf(s.w + bb.w, 0.f);
    *reinterpret_cast<float4*>(&H3[row * H3DIM + col]) = s;
}

// ---------------- scores: h1 = relu(sum_ks P[.][0:256] + b1); softmax(h1 @ w2 + b2) --------
__global__ __launch_bounds__(128) void scores_softmax_kernel(
    const float* __restrict__ P, const float* __restrict__ b1,
    const float* __restrict__ w2, const float* __restrict__ b2,
    float* __restrict__ probs)
{
    const int r = blockIdx.x;
    const int t = threadIdx.x;
    __shared__ float h[H1DIM];
    __shared__ float lg[CC];
    __shared__ float red[128];

    for (int k = t; k < H1DIM; k += 128) {
        float s = P[(size_t)r * NCOMB + k];
#pragma unroll
        for (int ksplit = 1; ksplit < SKM; ksplit++)
            s += P[((size_t)ksplit * NR + r) * NCOMB + k];
        h[k] = fmaxf(s + b1[k], 0.f);
    }
    __syncthreads();

    if (t < CC) {
        float acc = b2[t];
        for (int k = 0; k < H1DIM; k++) acc += h[k] * w2[k * CC + t];
        lg[t] = acc;
    }
    __syncthreads();

    red[t] = (t < CC) ? lg[t] : -1e30f;
    __syncthreads();
    for (int s = 64; s > 0; s >>= 1) {
        if (t < s) red[t] = fmaxf(red[t], red[t + s]);
        __syncthreads();
    }
    float mx = red[0];
    __syncthreads();

    float e = 0.f;
    if (t < CC) e = expf(lg[t] - mx);
    red[t] = e;
    __syncthreads();
    for (int s = 64; s > 0; s >>= 1) {
        if (t < s) red[t] += red[t + s];
        __syncthreads();
    }
    float sum = red[0];

    if (t >= 1 && t < CC) probs[(t - 1) * NR + r] = e / sum;
}

// ---------------- deltas GEMM partials: Pd[ks][1024][324] = H3 @ w4 (K-chunk ks) ------------
__global__ __launch_bounds__(64) void gemm_delta_kernel(
    const float* __restrict__ H3, const float* __restrict__ w4, float* __restrict__ Pd)
{
    const int nb = blockIdx.x;
    const int mb = blockIdx.y;
    const int ks = blockIdx.z;
    const int colbase = nb * 64;
    const int row0 = mb * 64;
    const int kstart = ks * 64;

    __shared__ float As[32][64];
    __shared__ float Bs[32][64];
    const int t = threadIdx.x;
    const int tx = t & 7;
    const int ty = t >> 3;
    const int brow = t >> 4;
    const int bcol4 = (t & 15) * 4;
    const int bcol_src = min(colbase + bcol4, D4 - 4);

    float acc[8][8] = {};
    float4 ca[8], cb[8];
    const float* Ar = &H3[(row0 + t) * H3DIM + kstart];

#pragma unroll
    for (int j = 0; j < 8; j++) {
        ca[j] = *reinterpret_cast<const float4*>(&Ar[j * 4]);
        cb[j] = *reinterpret_cast<const float4*>(&w4[(kstart + brow + j * 4) * D4 + bcol_src]);
    }

    for (int kt = 0; kt < 2; kt++) {
#pragma unroll
        for (int j = 0; j < 8; j++) {
            As[j * 4 + 0][t] = ca[j].x;
            As[j * 4 + 1][t] = ca[j].y;
            As[j * 4 + 2][t] = ca[j].z;
            As[j * 4 + 3][t] = ca[j].w;
            *reinterpret_cast<float4*>(&Bs[brow + j * 4][bcol4]) = cb[j];
        }
        if (kt < 1) {
            const int kn = kstart + 32;
#pragma unroll
            for (int j = 0; j < 8; j++) {
                ca[j] = *reinterpret_cast<const float4*>(&Ar[32 + j * 4]);
                cb[j] = *reinterpret_cast<const float4*>(&w4[(kn + brow + j * 4) * D4 + bcol_src]);
            }
        }
#pragma unroll 8
        for (int kk = 0; kk < 32; kk++) {
            float4 a0 = *reinterpret_cast<const float4*>(&As[kk][ty * 8]);
            float4 a1 = *reinterpret_cast<const float4*>(&As[kk][ty * 8 + 4]);
            float4 b0 = *reinterpret_cast<const float4*>(&Bs[kk][tx * 8]);
            float4 b1 = *reinterpret_cast<const float4*>(&Bs[kk][tx * 8 + 4]);
            float av[8] = {a0.x, a0.y, a0.z, a0.w, a1.x, a1.y, a1.z, a1.w};
            float bv[8] = {b0.x, b0.y, b0.z, b0.w, b1.x, b1.y, b1.z, b1.w};
#pragma unroll
            for (int i = 0; i < 8; i++)
#pragma unroll
                for (int j = 0; j < 8; j++)
                    acc[i][j] += av[i] * bv[j];
        }
    }

    const int pcol0 = colbase + tx * 8;
#pragma unroll
    for (int i = 0; i < 8; i++) {
        const int row = row0 + ty * 8 + i;
        float* pr = &Pd[((size_t)ks * NR + row) * D4 + pcol0];
        if (pcol0 + 4 <= D4)
            *reinterpret_cast<float4*>(&pr[0]) = make_float4(acc[i][0], acc[i][1], acc[i][2], acc[i][3]);
        if (pcol0 + 8 <= D4)
            *reinterpret_cast<float4*>(&pr[4]) = make_float4(acc[i][4], acc[i][5], acc[i][6], acc[i][7]);
    }
}

// ---------------- per-class: ballot-compact -> broadcast rank -> decode(sum Pd) -> NMS ------
__global__ __launch_bounds__(512) void class_nms_kernel(
    const float* __restrict__ probs, const float* __restrict__ Pd,
    const float* __restrict__ b4, const float* __restrict__ rois,
    const float* __restrict__ im_info, float* __restrict__ out)
{
    const int c = blockIdx.x;
    const int t = threadIdx.x;
    const int lane = t & 63;
    const int wave = t >> 6;

    __shared__ float imv[3];
    __shared__ float cs_sc[NR];
    __shared__ int   cs_ix[NR];
    __shared__ float ss[NR];
    __shared__ int   sx[NR];
    __shared__ float bx[NR][4];
    __shared__ int   kept_pos[NR];
    __shared__ u64 over64[64];
    __shared__ u64 presup_w;
    __shared__ u64 keep_w[16];
    __shared__ int vcount;
    __shared__ int kcount;

    if (t < 3) imv[t] = im_info[t];
    if (t < 16) keep_w[t] = 0ULL;
    if (t == 0) { vcount = 0; kcount = 0; presup_w = 0ULL; }
    __syncthreads();

    // ballot-compact valid entries (one atomic per wave)
    for (int i = t; i < NR; i += 512) {
        float s = probs[c * NR + i];
        bool valid = (s > 0.05f);
        u64 m = __ballot(valid ? 1 : 0);
        int wbase = 0;
        if (lane == 0 && m) wbase = atomicAdd(&vcount, __popcll(m));
        wbase = __shfl(wbase, 0, 64);
        if (valid) {
            int p = wbase + __popcll(m & ((1ULL << lane) - 1ULL));
            cs_sc[p] = s; cs_ix[p] = i;
        }
    }
    __syncthreads();
    const int V = vcount;

    // thread-per-entry exact stable rank; inner loop is an LDS broadcast
    for (int e = t; e < V; e += 512) {
        const float se = cs_sc[e];
        const int   ie = cs_ix[e];
        int cnt = 0;
        for (int f = 0; f < V; f++) {
            float sf = cs_sc[f];
            int   jf = cs_ix[f];
            cnt += (sf > se || (sf == se && jf < ie)) ? 1 : 0;
        }
        ss[cnt] = se; sx[cnt] = ie;
    }
    __syncthreads();

    // decode: one thread per sorted valid entry; sum the 8 Pd partials + b4
    const float Hm1 = imv[0] - 1.f, Wm1 = imv[1] - 1.f, inv = 1.f / imv[2];
    for (int i = t; i < V; i += 512) {
        const int r = sx[i];
        float4 dd = *reinterpret_cast<const float4*>(&Pd[(size_t)r * D4 + (c + 1) * 4]);
#pragma unroll
        for (int ksplit = 1; ksplit < SKD; ksplit++) {
            float4 p = *reinterpret_cast<const float4*>(&Pd[((size_t)ksplit * NR + r) * D4 + (c + 1) * 4]);
            dd.x += p.x; dd.y += p.y; dd.z += p.z; dd.w += p.w;
        }
        float4 b4c = *reinterpret_cast<const float4*>(&b4[(c + 1) * 4]);
        float dx = (dd.x + b4c.x) * 0.1f, dy = (dd.y + b4c.y) * 0.1f;
        float dw = (dd.z + b4c.z) * 0.2f, dh = (dd.w + b4c.w) * 0.2f;
        float x1 = rois[r * 5 + 1], y1 = rois[r * 5 + 2];
        float x2 = rois[r * 5 + 3], y2 = rois[r * 5 + 4];
        float wdt = x2 - x1 + 1.f, hgt = y2 - y1 + 1.f;
        float ctx = x1 + 0.5f * wdt, cty = y1 + 0.5f * hgt;
        float pcx = dx * wdt + ctx, pcy = dy * hgt + cty;
        float pw = expf(dw) * wdt, ph = expf(dh) * hgt;
        bx[i][0] = fminf(fmaxf(pcx - 0.5f * pw, 0.f), Wm1) * inv;
        bx[i][1] = fminf(fmaxf(pcy - 0.5f * ph, 0.f), Hm1) * inv;
        bx[i][2] = fminf(fmaxf(pcx + 0.5f * pw, 0.f), Wm1) * inv;
        bx[i][3] = fminf(fmaxf(pcy + 0.5f * ph, 0.f), Hm1) * inv;
    }
    __syncthreads();

    // NMS in 64-chunks: presup vs kept-list, ballot overlap matrix, readlane greedy scan
    for (int cs = 0; cs < V; cs += 64) {
        const int n = min(64, V - cs);
        const int ksnap = kcount;

        for (int i = wave; i < n; i += 8) {
            const int gi = cs + i;
            const float x1i = bx[gi][0], y1i = bx[gi][1], x2i = bx[gi][2], y2i = bx[gi][3];
            const float ai = (x2i - x1i + 1.f) * (y2i - y1i + 1.f);

            int sup = 0;
            for (int u = lane; u < ksnap; u += 64) {
                const int j = kept_pos[u];
                float iw = fminf(x2i, bx[j][2]) - fmaxf(x1i, bx[j][0]) + 1.f;
                float ih = fminf(y2i, bx[j][3]) - fmaxf(y1i, bx[j][1]) + 1.f;
                if (iw > 0.f && ih > 0.f) {
                    float inter = iw * ih;
                    float aj = (bx[j][2] - bx[j][0] + 1.f) * (bx[j][3] - bx[j][1] + 1.f);
                    if (inter / (ai + aj - inter) > 0.3f) sup = 1;
                }
            }
            int anysup = __any(sup);
            if (anysup && lane == 0) atomicOr(&presup_w, 1ULL << i);

            int pred = 0;
            if (lane < n) {
                const int gj = cs + lane;
                float iw = fminf(x2i, bx[gj][2]) - fmaxf(x1i, bx[gj][0]) + 1.f;
                float ih = fminf(y2i, bx[gj][3]) - fmaxf(y1i, bx[gj][1]) + 1.f;
                if (iw > 0.f && ih > 0.f) {
                    float inter = iw * ih;
                    float aj = (bx[gj][2] - bx[gj][0] + 1.f) * (bx[gj][3] - bx[gj][1] + 1.f);
                    if (inter / (ai + aj - inter) > 0.3f) pred = 1;
                }
            }
            u64 bits = __ballot(pred);
            if (lane == 0) over64[i] = bits;
        }
        __syncthreads();

        // greedy scan: rows pulled via v_readlane (no LDS / ballot round-trips)
        if (wave == 0) {
            u64 row = over64[lane];
            unsigned int rlo = (unsigned int)row;
            unsigned int rhi = (unsigned int)(row >> 32);
            u64 validm = (n >= 64) ? ~0ULL : ((1ULL << n) - 1ULL);
            u64 alive = validm & ~presup_w;
            u64 kept = 0ULL;
#pragma unroll
            for (int i = 0; i < 64; i++) {
                u64 ri =
                    ((u64)(unsigned int)__builtin_amdgcn_readlane(rhi, i) << 32) |
                    (unsigned int)__builtin_amdgcn_readlane(rlo, i);
                if ((alive >> i) & 1ULL) { kept |= 1ULL << i; alive &= ~ri; }
            }
            bool mykeep = (kept >> lane) & 1ULL;
            int kb = 0;
            if (lane == 0) {
                keep_w[cs >> 6] = kept;
                presup_w = 0ULL;
                kb = kcount;
                kcount = kb + __popcll(kept);
            }
            kb = __shfl(kb, 0, 64);
            if (mykeep) kept_pos[kb + __popcll(kept & ((1ULL << lane) - 1ULL))] = cs + lane;
        }
        __syncthreads();
    }

    // emit dets[c][i][6]
    for (int i = t; i < NR; i += 512) {
        float2* o = reinterpret_cast<float2*>(&out[(size_t)(c * NR + i) * 6]);
        bool kp = (i < V) && ((keep_w[i >> 6] >> (i & 63)) & 1ULL);
        float2 p0, p1, p2;
        if (kp) {
            p0 = make_float2(bx[i][0], bx[i][1]);
            p1 = make_float2(bx[i][2], bx[i][3]);
            p2 = make_float2(ss[i], (float)c);
        } else {
            p0 = make_float2(0.f, 0.f);
            p1 = make_float2(0.f, 0.f);
            p2 = make_float2(0.f, 0.f);
        }
        o[0] = p0; o[1] = p1; o[2] = p2;
    }
}

extern "C" void kernel_launch(void* const* d_in, const int* in_sizes, int n_in,
                              void* d_out, int out_size, void* d_ws, size_t ws_size,
                              hipStream_t stream)
{
    const float* X    = (const float*)d_in[0];
    const float* rois = (const float*)d_in[1];
    const float* imi  = (const float*)d_in[2];
    const float* w1   = (const float*)d_in[3];
    const float* b1   = (const float*)d_in[4];
    const float* w2   = (const float*)d_in[5];
    const float* b2   = (const float*)d_in[6];
    const float* w3   = (const float*)d_in[7];
    const float* b3   = (const float*)d_in[8];
    const float* w4   = (const float*)d_in[9];
    const float* b4   = (const float*)d_in[10];
    float* out = (float*)d_out;

    float* ws    = (float*)d_ws;
    float* H3    = ws;                         // 1024*512
    float* probs = H3 + NR * H3DIM;            // 80*1024
    float* P     = probs + NFG * NR;           // 4*1024*768 floats (Pd aliases)

    gemm_main_kernel<<<768, 128, 0, stream>>>(X, w1, w3, P);
    reduce_h3_kernel<<<(NR * H3DIM / 4 + 255) / 256, 256, 0, stream>>>(P, b3, H3);
    scores_softmax_kernel<<<NR, 128, 0, stream>>>(P, b1, w2, b2, probs);
    gemm_delta_kernel<<<dim3(6, 16, SKD), 64, 0, stream>>>(H3, w4, P);
    class_nms_kernel<<<NFG, 512, 0, stream>>>(probs, P, b4, rois, imi, out);
}